// Round 11
// baseline (240.255 us; speedup 1.0000x reference)
//
#include <hip/hip_runtime.h>

#define N_NODES 4096
#define HID 512
#define HEADS 8
#define DH 64
#define EPS 1e-5f
#define MAXD 128

typedef __attribute__((ext_vector_type(8))) short bf16x8;
typedef __attribute__((ext_vector_type(4))) float f32x4;

__device__ __forceinline__ unsigned short f2bf(float f) {
    unsigned int u = __float_as_uint(f);
    unsigned int r = (u + 0x7FFFu + ((u >> 16) & 1u)) >> 16;   // RNE
    return (unsigned short)r;
}
__device__ __forceinline__ float blo(unsigned int u) {        // low bf16 -> f32
    return __uint_as_float(u << 16);
}
__device__ __forceinline__ float bhi(unsigned int u) {        // high bf16 -> f32
    return __uint_as_float(u & 0xffff0000u);
}

__device__ __forceinline__ void gld_lds16(const void* g, void* l) {
    __builtin_amdgcn_global_load_lds(
        (const __attribute__((address_space(1))) unsigned int*)g,
        (__attribute__((address_space(3))) unsigned int*)l, 16, 0, 0);
}

// Fragment-packed layout: element (m,k) of [M][K] K-major at
//   ((m>>4)*(K>>5) + (k>>5))*512 + ((k>>3)&3)*128 + (m&15)*8 + (k&7)
// -> one bf16x8/lane = one contiguous 1KB wave transaction.

// ---------------------------------------------------------------------------
// bf16 MFMA GEMM, R10 structure (B staged via global_load_lds into 8KB LDS,
// conflict-free XOR swizzle; A direct global->VGPR dbuf), plus fused BN:
// AMODE: 0 = A row-major bf16 ; 1 = A fragment-packed bf16 ;
//        2 = A row-major f32 with BN applied on load (scale/shift LUT in LDS
//            built from bsum/bsumsq/bg/bb — this FUSES the bn_apply kernel)
// EPI:   0 = bias->bf16 ; 1 = bias+relu->bf16 ; 2 = bias+res(f32)->f32+stats
//        4 = bias + BN1(res_f32) residual ->f32+stats (FFN2; fp32-exact res)
// K is a TEMPLATE param; K-loop fully unrolled (R9: runtime buffer index ->
// scratch spill, 511us/dispatch).
// ---------------------------------------------------------------------------
template<int TM, int EPI, int AMODE, int K>
__global__ __launch_bounds__(256) void gemm_h(
    const unsigned short* __restrict__ Xb, const float* __restrict__ Xf,
    const unsigned short* __restrict__ Wt,
    const float* __restrict__ bias, const float* __restrict__ res,
    float* __restrict__ outf, unsigned short* __restrict__ outb,
    float* __restrict__ sum, float* __restrict__ sumsq,
    const float* __restrict__ bsum, const float* __restrict__ bsumsq,
    const float* __restrict__ bg, const float* __restrict__ bb,
    int Nc)
{
    constexpr int WM = TM / 64;                    // 16-row mfma tiles per wave
    constexpr int KC = K >> 5;
    constexpr int NS = K >> 6;
    __shared__ __align__(16) unsigned short Bs[64 * 64];          // 8 KB
    __shared__ float2 lut[(AMODE == 2) ? K : 4];                  // BN LUT

    const int tid = threadIdx.x;
    const int lane = tid & 63;
    const int wv = tid >> 6;
    const int m0 = blockIdx.y * TM, n0 = blockIdx.x * 64;
    const int lc = lane & 15, lq = lane >> 4;
    const int wrow = m0 + wv * (TM / 4);

    const int srow = tid >> 3;
    const int schunk = (tid & 7) ^ (srow & 7);
    unsigned short* ldsB = Bs + tid * 8;

    const unsigned short* paf = Xb + ((size_t)(wrow >> 4) * KC) * 512 + lane * 8;
    const unsigned short* par = Xb + (size_t)(wrow + lc) * K + lq * 8;
    const float* parf = Xf + (size_t)(wrow + lc) * K + lq * 8;

    if (AMODE == 2) {
        #pragma unroll
        for (int c = tid; c < K; c += 256) {
            float m = bsum[c] * (1.0f / N_NODES);
            float v = bsumsq[c] * (1.0f / N_NODES) - m * m;
            float iv = rsqrtf(v + EPS);
            float sc = bg[c] * iv;
            lut[c] = make_float2(sc, bb[c] - sc * m);
        }
        __syncthreads();
    }

    bf16x8 afb[2][WM][2];
    f32x4 acc[WM][4] = {};

#define LOAD_A(S, BUF)                                                          \
    if (AMODE != 2) {                                                           \
        _Pragma("unroll")                                                       \
        for (int i = 0; i < WM; ++i)                                            \
            _Pragma("unroll")                                                   \
            for (int h = 0; h < 2; ++h)                                         \
                afb[BUF][i][h] = (AMODE == 1)                                   \
                    ? *(const bf16x8*)(paf + ((size_t)i * KC + 2 * (S) + h) * 512) \
                    : *(const bf16x8*)(par + (size_t)(i * 16) * K + (S) * 64 + h * 32); \
    }

    LOAD_A(0, 0)
    #pragma unroll
    for (int s = 0; s < NS; ++s) {
        const unsigned short* gB = Wt + (size_t)(n0 + srow) * K + s * 64 + schunk * 8;
        gld_lds16(gB, ldsB);
        gld_lds16(gB + (size_t)32 * K, ldsB + 2048);
        __syncthreads();

        if (s + 1 < NS) { LOAD_A(s + 1, ((s & 1) ^ 1)) }

        bf16x8 afx[WM][2];
        if (AMODE == 2) {
            #pragma unroll
            for (int i = 0; i < WM; ++i)
                #pragma unroll
                for (int h = 0; h < 2; ++h) {
                    const float* p = parf + (size_t)(i * 16) * K + s * 64 + h * 32;
                    float4 f0 = *(const float4*)p;
                    float4 f1 = *(const float4*)(p + 4);
                    const int kb = s * 64 + h * 32 + lq * 8;
                    float2 l0 = lut[kb], l1 = lut[kb + 1], l2 = lut[kb + 2], l3 = lut[kb + 3];
                    float2 l4 = lut[kb + 4], l5 = lut[kb + 5], l6 = lut[kb + 6], l7 = lut[kb + 7];
                    uint4 uu;
                    uu.x = (unsigned int)f2bf(f0.x * l0.x + l0.y) | ((unsigned int)f2bf(f0.y * l1.x + l1.y) << 16);
                    uu.y = (unsigned int)f2bf(f0.z * l2.x + l2.y) | ((unsigned int)f2bf(f0.w * l3.x + l3.y) << 16);
                    uu.z = (unsigned int)f2bf(f1.x * l4.x + l4.y) | ((unsigned int)f2bf(f1.y * l5.x + l5.y) << 16);
                    uu.w = (unsigned int)f2bf(f1.z * l6.x + l6.y) | ((unsigned int)f2bf(f1.w * l7.x + l7.y) << 16);
                    afx[i][h] = *(bf16x8*)&uu;
                }
        }

        bf16x8 bfr[4][2];
        #pragma unroll
        for (int j = 0; j < 4; ++j)
            #pragma unroll
            for (int h = 0; h < 2; ++h)
                bfr[j][h] = *(const bf16x8*)&Bs[(j * 16 + lc) * 64 + ((h * 4 + lq) ^ (lc & 7)) * 8];

        #pragma unroll
        for (int h = 0; h < 2; ++h)
            #pragma unroll
            for (int i = 0; i < WM; ++i)
                #pragma unroll
                for (int j = 0; j < 4; ++j)
                    acc[i][j] = __builtin_amdgcn_mfma_f32_16x16x32_bf16(
                        (AMODE == 2) ? afx[i][h] : afb[s & 1][i][h],
                        bfr[j][h], acc[i][j], 0, 0, 0);
        __syncthreads();
    }
#undef LOAD_A

    // epilogue
    float scj[4], shj[4];
    if (EPI == 4) {
        #pragma unroll
        for (int j = 0; j < 4; ++j) {
            const int gc = n0 + j * 16 + lc;
            float m = bsum[gc] * (1.0f / N_NODES);
            float v = bsumsq[gc] * (1.0f / N_NODES) - m * m;
            float iv = rsqrtf(v + EPS);
            scj[j] = bg[gc] * iv;
            shj[j] = bb[gc] - scj[j] * m;
        }
    }

    float cs[4] = {}, css[4] = {};
    #pragma unroll
    for (int i = 0; i < WM; ++i) {
        #pragma unroll
        for (int j = 0; j < 4; ++j) {
            const int gr0 = wrow + i * 16 + lq * 4;
            const int gc = n0 + j * 16 + lc;
            const float bi = bias[gc];
            #pragma unroll
            for (int r = 0; r < 4; ++r) {
                float val = acc[i][j][r] + bi;
                size_t off = (size_t)(gr0 + r) * Nc + gc;
                if (EPI == 0)      outb[off] = f2bf(val);
                else if (EPI == 1) outb[off] = f2bf(fmaxf(val, 0.f));
                else {
                    if (EPI == 2) val += res[off];
                    else          val += scj[j] * res[off] + shj[j];  // BN1(x1)
                    outf[off] = val;
                    cs[j] += val; css[j] += val * val;
                }
            }
        }
    }
    if (EPI >= 2) {
        #pragma unroll
        for (int j = 0; j < 4; ++j) {
            float s = cs[j], ss = css[j];
            s += __shfl_xor(s, 16); s += __shfl_xor(s, 32);
            ss += __shfl_xor(ss, 16); ss += __shfl_xor(ss, 32);
            if (lq == 0) {
                const int gc = n0 + j * 16 + lc;
                atomicAdd(&sum[gc], s);
                atomicAdd(&sumsq[gc], ss);
            }
        }
    }
}

// ---------------------------------------------------------------------------
// Fused prep: z=0..5 weight transpose -> K-major bf16; z=6 h -> frag-packed
// bf16; z=7 bias concat + stat zero
// ---------------------------------------------------------------------------
__global__ __launch_bounds__(256) void prep_all(
    const float* __restrict__ Wq, const float* __restrict__ Wk,
    const float* __restrict__ Wv, const float* __restrict__ Wo,
    const float* __restrict__ W1, const float* __restrict__ W2,
    const float* __restrict__ h,
    const float* __restrict__ bq, const float* __restrict__ bk,
    const float* __restrict__ bv,
    unsigned short* __restrict__ wqkvT, unsigned short* __restrict__ woT,
    unsigned short* __restrict__ w1T, unsigned short* __restrict__ w2T,
    unsigned int* __restrict__ hb, float* __restrict__ bqkv,
    float* __restrict__ st)
{
    const int z = blockIdx.z;
    if (z < 6) {
        const float* in; unsigned short* out; int R, C;
        switch (z) {
            case 0: in = Wq; out = wqkvT;          R = 512;  C = 512;  break;
            case 1: in = Wk; out = wqkvT + 262144; R = 512;  C = 512;  break;
            case 2: in = Wv; out = wqkvT + 524288; R = 512;  C = 512;  break;
            case 3: in = Wo; out = woT;            R = 512;  C = 512;  break;
            case 4: in = W1; out = w1T;            R = 512;  C = 1024; break;
            default: in = W2; out = w2T;           R = 1024; C = 512;  break;
        }
        const int bc = blockIdx.x * 32, br = blockIdx.y * 32;
        if (bc >= C || br >= R) return;
        __shared__ float tile[32][33];
        const int tx = threadIdx.x & 31, ty = threadIdx.x >> 5;
        #pragma unroll
        for (int r = ty; r < 32; r += 8)
            tile[r][tx] = in[(size_t)(br + r) * C + bc + tx];
        __syncthreads();
        #pragma unroll
        for (int r = ty; r < 32; r += 8)
            out[(size_t)(bc + r) * R + br + tx] = f2bf(tile[tx][r]);
    } else if (z == 6) {
        const int blk = blockIdx.y * 32 + blockIdx.x;
        const int i = blk * 512 + threadIdx.x * 2;   // even float4 index
        const float4* in4 = (const float4*)h;
        float4 f0 = in4[i], f1 = in4[i + 1];
        uint4 w;
        w.x = (unsigned int)f2bf(f0.x) | ((unsigned int)f2bf(f0.y) << 16);
        w.y = (unsigned int)f2bf(f0.z) | ((unsigned int)f2bf(f0.w) << 16);
        w.z = (unsigned int)f2bf(f1.x) | ((unsigned int)f2bf(f1.y) << 16);
        w.w = (unsigned int)f2bf(f1.z) | ((unsigned int)f2bf(f1.w) << 16);
        const int m = i >> 7, k = (i & 127) * 4;
        const size_t off_u4 = ((size_t)(m >> 4) * 16 + (k >> 5)) * 64
                            + ((k >> 3) & 3) * 16 + (m & 15);
        ((uint4*)hb)[off_u4] = w;
    } else {
        const int blk = blockIdx.y * 32 + blockIdx.x;
        const int i = blk * 256 + threadIdx.x;
        if (i < 1536) bqkv[i] = i < 512 ? bq[i] : (i < 1024 ? bk[i - 512] : bv[i - 1024]);
        if (i < 2048) st[i] = 0.0f;
    }
}

// ---------------------------------------------------------------------------
// Sparse attention v7: attn5's proven structure (44us stable), output o in
// FRAGMENT-PACKED layout so O-proj's A loads are 1KB coalesced.
// NO bulk K/V LDS staging (v3's 1-block/CU cliff).
// ---------------------------------------------------------------------------
__global__ __launch_bounds__(256) void sparse_attn7(
    const float* __restrict__ A, const unsigned short* __restrict__ qkv,
    unsigned short* __restrict__ o)
{
    const int n = blockIdx.x;
    const int tid = threadIdx.x;
    const int wv = tid >> 6, lane = tid & 63;

    __shared__ int s_idx[MAXD];
    __shared__ float s_p[8][MAXD];
    __shared__ int s_cnt[4];

    // ---- inline adjacency ----
    const float4* r4 = (const float4*)(A + (size_t)n * N_NODES);
    float4 av[4];
    #pragma unroll
    for (int t = 0; t < 4; ++t)
        av[t] = r4[wv * 256 + t * 64 + lane];

    const unsigned long long lt = (1ull << lane) - 1ull;
    int cnt = 0;
    #pragma unroll
    for (int t = 0; t < 4; ++t) {
        #pragma unroll
        for (int b = 0; b < 4; ++b) {
            float vb = (b == 0) ? av[t].x : (b == 1) ? av[t].y : (b == 2) ? av[t].z : av[t].w;
            cnt += __popcll(__ballot(vb > 0.0f));
        }
    }
    if (lane == 0) s_cnt[wv] = cnt;
    __syncthreads();
    int base = 0, total = 0;
    #pragma unroll
    for (int w = 0; w < 4; ++w) {
        if (w < wv) base += s_cnt[w];
        total += s_cnt[w];
    }
    const int d = total < MAXD ? total : MAXD;
    #pragma unroll
    for (int t = 0; t < 4; ++t) {
        #pragma unroll
        for (int b = 0; b < 4; ++b) {
            float vb = (b == 0) ? av[t].x : (b == 1) ? av[t].y : (b == 2) ? av[t].z : av[t].w;
            unsigned long long m = __ballot(vb > 0.0f);
            if (vb > 0.0f) {
                int p = base + __popcll(m & lt);
                if (p < MAXD) s_idx[p] = wv * 1024 + t * 256 + lane * 4 + b;
            }
            base += __popcll(m);
        }
    }
    __syncthreads();

    // ---- scores ----
    const int jl = lane >> 3;
    const int dgs = lane & 7;
    const int h0 = wv, h1 = wv + 4;

    const unsigned short* qp = qkv + (size_t)n * 1536 + dgs * 8;
    uint4 qa = *(const uint4*)(qp + h0 * 64);
    uint4 qb = *(const uint4*)(qp + h1 * 64);
    const float a0 = blo(qa.x), a1 = bhi(qa.x), a2 = blo(qa.y), a3 = bhi(qa.y);
    const float a4 = blo(qa.z), a5 = bhi(qa.z), a6 = blo(qa.w), a7 = bhi(qa.w);
    const float b0 = blo(qb.x), b1 = bhi(qb.x), b2 = blo(qb.y), b3 = bhi(qb.y);
    const float b4 = blo(qb.z), b5 = bhi(qb.z), b6 = blo(qb.w), b7 = bhi(qb.w);

    uint4 ka = {0, 0, 0, 0}, kb = {0, 0, 0, 0};
    if (jl < d) {
        const unsigned short* p = qkv + (size_t)s_idx[jl] * 1536 + 512 + dgs * 8;
        ka = *(const uint4*)(p + h0 * 64);
        kb = *(const uint4*)(p + h1 * 64);
    }
    for (int j0 = 0; j0 < d; j0 += 8) {
        const uint4 ca = ka, cb = kb;
        const int jn = j0 + 8 + jl;
        if (jn < d) {
            const unsigned short* p = qkv + (size_t)s_idx[jn] * 1536 + 512 + dgs * 8;
            ka = *(const uint4*)(p + h0 * 64);
            kb = *(const uint4*)(p + h1 * 64);
        }
        const int jc = j0 + jl;
        float s0 = 0.f, s1 = 0.f;
        if (jc < d) {
            s0 = a0 * blo(ca.x) + a1 * bhi(ca.x) + a2 * blo(ca.y) + a3 * bhi(ca.y)
               + a4 * blo(ca.z) + a5 * bhi(ca.z) + a6 * blo(ca.w) + a7 * bhi(ca.w);
            s1 = b0 * blo(cb.x) + b1 * bhi(cb.x) + b2 * blo(cb.y) + b3 * bhi(cb.y)
               + b4 * blo(cb.z) + b5 * bhi(cb.z) + b6 * blo(cb.w) + b7 * bhi(cb.w);
        }
        s0 += __shfl_xor(s0, 1); s1 += __shfl_xor(s1, 1);
        s0 += __shfl_xor(s0, 2); s1 += __shfl_xor(s1, 2);
        s0 += __shfl_xor(s0, 4); s1 += __shfl_xor(s1, 4);
        if (dgs == 0 && jc < d) {
            s_p[h0][jc] = s0 * 0.125f;    // 1/sqrt(64)
            s_p[h1][jc] = s1 * 0.125f;
        }
    }

    // ---- softmax per head ----
    float inv0, inv1;
    #pragma unroll
    for (int hh = 0; hh < 2; ++hh) {
        float* sp = s_p[hh ? h1 : h0];
        float mx = -1e30f;
        for (int j = lane; j < d; j += 64) mx = fmaxf(mx, sp[j]);
        #pragma unroll
        for (int off = 32; off; off >>= 1) mx = fmaxf(mx, __shfl_xor(mx, off));
        float sum = 0.f;
        for (int j = lane; j < d; j += 64) {
            float e = __expf(sp[j] - mx);
            sp[j] = e;
            sum += e;
        }
        #pragma unroll
        for (int off = 32; off; off >>= 1) sum += __shfl_xor(sum, off);
        if (hh) inv1 = 1.0f / sum; else inv0 = 1.0f / sum;
    }

    // ---- accumulate (attn5 form: 4 nbr-lanes x 4 dims, uint2, prefetch) ----
    const int jl2 = lane >> 4;
    const int dga = lane & 15;
    float x0 = 0.f, x1 = 0.f, x2 = 0.f, x3 = 0.f;
    float y0 = 0.f, y1 = 0.f, y2 = 0.f, y3 = 0.f;
    uint2 va = {0, 0}, vb = {0, 0};
    if (jl2 < d) {
        const unsigned short* p = qkv + (size_t)s_idx[jl2] * 1536 + 1024 + dga * 4;
        va = *(const uint2*)(p + h0 * 64);
        vb = *(const uint2*)(p + h1 * 64);
    }
    for (int j0 = 0; j0 < d; j0 += 4) {
        const uint2 ca = va, cb = vb;
        const int jn = j0 + 4 + jl2;
        if (jn < d) {
            const unsigned short* p = qkv + (size_t)s_idx[jn] * 1536 + 1024 + dga * 4;
            va = *(const uint2*)(p + h0 * 64);
            vb = *(const uint2*)(p + h1 * 64);
        }
        const int jc = j0 + jl2;
        if (jc < d) {
            const float p0 = s_p[h0][jc], p1 = s_p[h1][jc];
            x0 += p0 * blo(ca.x); x1 += p0 * bhi(ca.x);
            x2 += p0 * blo(ca.y); x3 += p0 * bhi(ca.y);
            y0 += p1 * blo(cb.x); y1 += p1 * bhi(cb.x);
            y2 += p1 * blo(cb.y); y3 += p1 * bhi(cb.y);
        }
    }
    x0 += __shfl_xor(x0, 16); x0 += __shfl_xor(x0, 32);
    x1 += __shfl_xor(x1, 16); x1 += __shfl_xor(x1, 32);
    x2 += __shfl_xor(x2, 16); x2 += __shfl_xor(x2, 32);
    x3 += __shfl_xor(x3, 16); x3 += __shfl_xor(x3, 32);
    y0 += __shfl_xor(y0, 16); y0 += __shfl_xor(y0, 32);
    y1 += __shfl_xor(y1, 16); y1 += __shfl_xor(y1, 32);
    y2 += __shfl_xor(y2, 16); y2 += __shfl_xor(y2, 32);
    y3 += __shfl_xor(y3, 16); y3 += __shfl_xor(y3, 32);
    if (jl2 == 0) {
        // frag-packed write: (n, k) -> ((n>>4)*16+(k>>5))*512+((k>>3)&3)*128+(n&15)*8+(k&7)
        uint2 w0, w1;
        w0.x = (unsigned int)f2bf(x0 * inv0) | ((unsigned int)f2bf(x1 * inv0) << 16);
        w0.y = (unsigned int)f2bf(x2 * inv0) | ((unsigned int)f2bf(x3 * inv0) << 16);
        w1.x = (unsigned int)f2bf(y0 * inv1) | ((unsigned int)f2bf(y1 * inv1) << 16);
        w1.y = (unsigned int)f2bf(y2 * inv1) | ((unsigned int)f2bf(y3 * inv1) << 16);
        const int k0 = h0 * 64 + dga * 4;
        const int k1 = h1 * 64 + dga * 4;
        const size_t base_n = (size_t)(n >> 4) * 16 * 512 + (n & 15) * 8;
        *(uint2*)(o + base_n + (size_t)(k0 >> 5) * 512 + ((k0 >> 3) & 3) * 128 + (k0 & 7)) = w0;
        *(uint2*)(o + base_n + (size_t)(k1 >> 5) * 512 + ((k1 >> 3) & 3) * 128 + (k1 & 7)) = w1;
    }
}

// ---------------------------------------------------------------------------
// BatchNorm apply (only BN2 now; BN1 is fused into FFN1/FFN2)
// ---------------------------------------------------------------------------
__global__ __launch_bounds__(256) void bn_apply4(
    const float4* __restrict__ x, const float* __restrict__ sum,
    const float* __restrict__ sumsq, const float* __restrict__ g,
    const float* __restrict__ b, float4* __restrict__ yf)
{
    const int i = blockIdx.x * 256 + threadIdx.x;
    const int c4 = i & 127;
    const float4 s4 = ((const float4*)sum)[c4];
    const float4 q4 = ((const float4*)sumsq)[c4];
    const float4 g4 = ((const float4*)g)[c4];
    const float4 b4 = ((const float4*)b)[c4];
    const float4 xv = x[i];
    const float kN = 1.0f / N_NODES;
    float4 r;
    { float m = s4.x * kN; r.x = g4.x * (xv.x - m) * rsqrtf(q4.x * kN - m * m + EPS) + b4.x; }
    { float m = s4.y * kN; r.y = g4.y * (xv.y - m) * rsqrtf(q4.y * kN - m * m + EPS) + b4.y; }
    { float m = s4.z * kN; r.z = g4.z * (xv.z - m) * rsqrtf(q4.z * kN - m * m + EPS) + b4.z; }
    { float m = s4.w * kN; r.w = g4.w * (xv.w - m) * rsqrtf(q4.w * kN - m * m + EPS) + b4.w; }
    yf[i] = r;
}

// ---------------------------------------------------------------------------

extern "C" void kernel_launch(void* const* d_in, const int* in_sizes, int n_in,
                              void* d_out, int out_size, void* d_ws, size_t ws_size,
                              hipStream_t stream)
{
    const float* A   = (const float*)d_in[0];
    const float* h   = (const float*)d_in[1];
    const float* Wq  = (const float*)d_in[2];
    const float* bq  = (const float*)d_in[3];
    const float* Wk  = (const float*)d_in[4];
    const float* bk  = (const float*)d_in[5];
    const float* Wv  = (const float*)d_in[6];
    const float* bv  = (const float*)d_in[7];
    const float* Wo  = (const float*)d_in[8];
    const float* bo  = (const float*)d_in[9];
    const float* g1  = (const float*)d_in[10];
    const float* b1g = (const float*)d_in[11];
    const float* g2  = (const float*)d_in[12];
    const float* b2g = (const float*)d_in[13];
    const float* W1  = (const float*)d_in[14];
    const float* b1  = (const float*)d_in[15];
    const float* W2  = (const float*)d_in[16];
    const float* b2  = (const float*)d_in[17];
    float* out = (float*)d_out;

    float* ws = (float*)d_ws;
    unsigned short* hb    = (unsigned short*)(ws);               // 4096x512 bf16 (frag)
    unsigned short* qkvb  = (unsigned short*)(ws + 1048576);     // 4096x1536 bf16
    unsigned short* o_bf  = (unsigned short*)(ws + 4194304);     // 4096x512 bf16 (frag)
    unsigned short* wqkvT = (unsigned short*)(ws + 5242880);     // 1536x512 bf16 K-major
    unsigned short* woT   = (unsigned short*)(ws + 5636096);     // 512x512 bf16 K-major
    unsigned short* w1T   = (unsigned short*)(ws + 5767168);     // 1024x512 bf16 K-major
    unsigned short* w2T   = (unsigned short*)(ws + 6029312);     // 512x1024 bf16 K-major
    unsigned short* t_b   = (unsigned short*)(ws + 6291456);     // 4096x1024 bf16
    float* x1   = ws + 8388608;                                   // 4096x512 f32
    float* x2   = ws + 10485760;                                  // 4096x512 f32
    float* bqkv = ws + 13631488;                                  // 1536
    float* st   = ws + 13633024;                                  // 2048

    // --- fused prep ---
    prep_all<<<dim3(32, 32, 8), dim3(256), 0, stream>>>(
        Wq, Wk, Wv, Wo, W1, W2, h, bq, bk, bv,
        wqkvT, woT, w1T, w2T, (unsigned int*)hb, bqkv, st);

    // --- fused QKV projection: 768 blocks, frag A ---
    gemm_h<128, 0, 1, 512><<<dim3(24, 32), dim3(256), 0, stream>>>(
        hb, nullptr, wqkvT, bqkv, nullptr, nullptr, qkvb,
        nullptr, nullptr, nullptr, nullptr, nullptr, nullptr, 1536);

    // --- sparse masked attention (inline adjacency, frag o) ---
    sparse_attn7<<<dim3(N_NODES), dim3(256), 0, stream>>>(A, qkvb, o_bf);

    // --- O projection + residual(h) + BN1 stats: 512 blocks, frag A ---
    gemm_h<64, 2, 1, 512><<<dim3(8, 64), dim3(256), 0, stream>>>(
        o_bf, nullptr, woT, bo, h, x1, nullptr,
        st, st + 512, nullptr, nullptr, nullptr, nullptr, 512);

    // --- FFN1 with FUSED BN1 on A (reads x1 f32 + stats): 512 blocks ---
    gemm_h<128, 1, 2, 512><<<dim3(16, 32), dim3(256), 0, stream>>>(
        nullptr, x1, w1T, b1, nullptr, nullptr, t_b,
        nullptr, nullptr, st, st + 512, g1, b1g, 1024);

    // --- FFN2 + FUSED BN1 residual + BN2 stats: 512 blocks ---
    gemm_h<64, 4, 0, 1024><<<dim3(8, 64), dim3(256), 0, stream>>>(
        t_b, nullptr, w2T, b2, x1, x2, nullptr,
        st + 1024, st + 1536, st, st + 512, g1, b1g, 512);

    // --- BN2 apply -> out ---
    bn_apply4<<<dim3(2048), dim3(256), 0, stream>>>(
        (const float4*)x2, st + 1024, st + 1536, g2, b2g, (float4*)out);

    (void)in_sizes; (void)n_in; (void)out_size; (void)ws_size;
}